// Round 2
// baseline (68.280 us; speedup 1.0000x reference)
//
#include <hip/hip_runtime.h>

// Problem constants (from reference setup_inputs).
#define KBINS 161
#define TFRAMES 2000
#define TILE_T 8                      // frames per block; 2000/8 = 250 blocks

// One block = all K bins x TILE_T consecutive frames.
// Math: out[j,t] = sum_i w(i,j,t) * x[i,t]
//   wide_i (am_i > 1): w = relu(am_i - |j-i|) / S_i,  S_i = sum_j relu(am_i - |j-i|)
//   else:              w = (i == j)
// The reference's /am^2 cancels under the row normalization.
__global__ __launch_bounds__(256) void m_noise_smooth_kernel(
    const float* __restrict__ m,   // (K, T, 1)
    const float* __restrict__ x,   // (1, 1, K, T)
    float* __restrict__ out) {     // (1, 1, K, T)
  const int t0 = blockIdx.x * TILE_T;
  const int tid = threadIdx.x;

  __shared__ float s_am[KBINS * TILE_T];     // |m[i, t0+t_]|
  __shared__ float s_scale[KBINS * TILE_T];  // wide ? 1/S : 0
  __shared__ float s_x[KBINS * TILE_T];      // x[i, t0+t_]
  __shared__ float s_wmax[4];                // per-wave max(am)

  float thread_max = 0.0f;

  // ---- Stage x: float4 coalesced (row = 8 floats = 2 float4) ----
  for (int q = tid; q < KBINS * 2; q += 256) {
    const int i = q >> 1;
    const int h = (q & 1) * 4;
    const float4 v = *(const float4*)(x + i * TFRAMES + t0 + h);
    *(float4*)(s_x + i * TILE_T + h) = v;
  }

  // ---- Stage m -> am, scale (float4 load + per-element S) ----
  for (int q = tid; q < KBINS * 2; q += 256) {
    const int i = q >> 1;
    const int h = (q & 1) * 4;
    const float4 v = *(const float4*)(m + i * TFRAMES + t0 + h);
    const float vv[4] = {v.x, v.y, v.z, v.w};
#pragma unroll
    for (int e = 0; e < 4; ++e) {
      const float am = fabsf(vv[e]);
      thread_max = fmaxf(thread_max, am);
      // Edge-truncated triangle mass: S = am + sum_{d=1}^{floor(am)} (am-d)*cnt
      float S = am;
      int dmax = (int)am;
      if (dmax > KBINS - 1) dmax = KBINS - 1;
      for (int d = 1; d <= dmax; ++d) {
        const int cnt = (i - d >= 0) + (i + d < KBINS);
        S += (am - (float)d) * (float)cnt;
      }
      s_am[i * TILE_T + h + e] = am;
      s_scale[i * TILE_T + h + e] = (am > 1.0f) ? (1.0f / S) : 0.0f;
    }
  }

  // ---- Block max(am) -> gather radius. One barrier total. ----
#pragma unroll
  for (int off = 32; off > 0; off >>= 1)
    thread_max = fmaxf(thread_max, __shfl_xor(thread_max, off, 64));
  if ((tid & 63) == 0) s_wmax[tid >> 6] = thread_max;
  __syncthreads();  // covers LDS staging writes + s_wmax
  const float maxam =
      fmaxf(fmaxf(s_wmax[0], s_wmax[1]), fmaxf(s_wmax[2], s_wmax[3]));
  int R = (int)ceilf(maxam);
  if (R > KBINS - 1) R = KBINS - 1;

  // ---- Gather: thread = (j, t_), lanes span 8 j's x 8 t's ----
  const int t_ = tid & 7;
  for (int j = (tid >> 3); j < KBINS; j += 32) {
    const int lo = (j - R > 0) ? (j - R) : 0;
    const int hi = (j + R < KBINS - 1) ? (j + R) : (KBINS - 1);
    const float sc_j = s_scale[j * TILE_T + t_];
    // Delta branch: non-wide source i contributes x[i,t] only at j == i.
    float acc = (sc_j == 0.0f) ? s_x[j * TILE_T + t_] : 0.0f;
    for (int i = lo; i <= hi; ++i) {
      // idx = i*8 + t_: across the wave this spans 64 consecutive words
      // -> 2-way bank aliasing, free on gfx950.
      const float w =
          fmaxf(s_am[i * TILE_T + t_] - fabsf((float)(j - i)), 0.0f) *
          s_scale[i * TILE_T + t_];
      acc = fmaf(w, s_x[i * TILE_T + t_], acc);
    }
    out[j * TFRAMES + t0 + t_] = acc;  // 32B-contiguous per row
  }
}

extern "C" void kernel_launch(void* const* d_in, const int* in_sizes, int n_in,
                              void* d_out, int out_size, void* d_ws, size_t ws_size,
                              hipStream_t stream) {
  const float* m = (const float*)d_in[0];  // (K, T, 1) fp32
  const float* x = (const float*)d_in[1];  // (1, 1, K, T) fp32
  // d_in[2] = input_length (unused by the reference math)
  float* out = (float*)d_out;              // (1, 1, K, T) fp32

  m_noise_smooth_kernel<<<TFRAMES / TILE_T, 256, 0, stream>>>(m, x, out);
}

// Round 3
// 65.697 us; speedup vs baseline: 1.0393x; 1.0393x over previous
//
#include <hip/hip_runtime.h>

// Problem constants (from reference setup_inputs).
#define KBINS 161
#define TFRAMES 2000
#define TILE_T 4                      // frames per block; 2000/4 = 500 blocks (~2/CU)

// One block = all K bins x TILE_T consecutive frames.
// Math: out[j,t] = sum_i w(i,j,t) * x[i,t]
//   wide_i (am_i > 1): w = relu(am_i - |j-i|) / S_i,  S_i = sum_j relu(am_i - |j-i|)
//   else:              w = (i == j)
// The reference's /am^2 cancels under the row normalization.
__global__ __launch_bounds__(256) void m_noise_smooth_kernel(
    const float* __restrict__ m,   // (K, T, 1)
    const float* __restrict__ x,   // (1, 1, K, T)
    float* __restrict__ out) {     // (1, 1, K, T)
  const int t0 = blockIdx.x * TILE_T;
  const int tid = threadIdx.x;

  __shared__ float s_am[KBINS * TILE_T];     // |m[i, t0+t_]|
  __shared__ float s_scale[KBINS * TILE_T];  // wide ? 1/S : 0
  __shared__ float s_x[KBINS * TILE_T];      // x[i, t0+t_]
  __shared__ float s_wmax[4];                // per-wave max(am)

  float thread_max = 0.0f;

  // ---- Stage x and m: one float4 per row (16B, coalesced) ----
  if (tid < KBINS) {
    const int i = tid;
    const float4 vx = *(const float4*)(x + i * TFRAMES + t0);
    *(float4*)(s_x + i * TILE_T) = vx;

    const float4 vm = *(const float4*)(m + i * TFRAMES + t0);
    const float vv[4] = {vm.x, vm.y, vm.z, vm.w};
#pragma unroll
    for (int e = 0; e < 4; ++e) {
      const float am = fabsf(vv[e]);
      thread_max = fmaxf(thread_max, am);
      // Edge-truncated triangle mass: S = am + sum_{d=1}^{floor(am)} (am-d)*cnt
      float S = am;
      int dmax = (int)am;
      if (dmax > KBINS - 1) dmax = KBINS - 1;
      for (int d = 1; d <= dmax; ++d) {
        const int cnt = (i - d >= 0) + (i + d < KBINS);
        S += (am - (float)d) * (float)cnt;
      }
      s_am[i * TILE_T + e] = am;
      s_scale[i * TILE_T + e] = (am > 1.0f) ? (1.0f / S) : 0.0f;
    }
  }

  // ---- Block max(am) -> gather radius. One barrier total. ----
#pragma unroll
  for (int off = 32; off > 0; off >>= 1)
    thread_max = fmaxf(thread_max, __shfl_xor(thread_max, off, 64));
  if ((tid & 63) == 0) s_wmax[tid >> 6] = thread_max;
  __syncthreads();  // covers LDS staging writes + s_wmax
  const float maxam =
      fmaxf(fmaxf(s_wmax[0], s_wmax[1]), fmaxf(s_wmax[2], s_wmax[3]));
  int R = (int)ceilf(maxam);
  if (R > KBINS - 1) R = KBINS - 1;

  // ---- Gather: thread = (j, t_); wave lanes = 16 j's x 4 t's ----
  const int t_ = tid & 3;
  for (int j = (tid >> 2); j < KBINS; j += 64) {
    const int lo = (j - R > 0) ? (j - R) : 0;
    const int hi = (j + R < KBINS - 1) ? (j + R) : (KBINS - 1);
    const float sc_j = s_scale[j * TILE_T + t_];
    // Delta branch: non-wide source i contributes x[i,t] only at j == i.
    float acc = (sc_j == 0.0f) ? s_x[j * TILE_T + t_] : 0.0f;
    for (int i = lo; i <= hi; ++i) {
      // idx = i*4 + t_: across the wave this spans 64 consecutive words
      // -> 2-way bank aliasing, free on gfx950.
      const float w =
          fmaxf(s_am[i * TILE_T + t_] - fabsf((float)(j - i)), 0.0f) *
          s_scale[i * TILE_T + t_];
      acc = fmaf(w, s_x[i * TILE_T + t_], acc);
    }
    out[j * TFRAMES + t0 + t_] = acc;  // 16B-contiguous per row
  }
}

extern "C" void kernel_launch(void* const* d_in, const int* in_sizes, int n_in,
                              void* d_out, int out_size, void* d_ws, size_t ws_size,
                              hipStream_t stream) {
  const float* m = (const float*)d_in[0];  // (K, T, 1) fp32
  const float* x = (const float*)d_in[1];  // (1, 1, K, T) fp32
  // d_in[2] = input_length (unused by the reference math)
  float* out = (float*)d_out;              // (1, 1, K, T) fp32

  m_noise_smooth_kernel<<<TFRAMES / TILE_T, 256, 0, stream>>>(m, x, out);
}